// Round 9
// baseline (1305.656 us; speedup 1.0000x reference)
//
#include <hip/hip_runtime.h>
#include <hip/hip_bf16.h>
#include <stdint.h>
#include <stddef.h>

// ---- model dims ----
#define Vv   32000
#define Dd   1024
#define NLay 2
#define Ss   2048
#define Nn   16
#define Kc   4
#define DIc  2048
#define EPSf 1e-5f
#define LCH  32
#define NCHc (Ss / LCH)   // 64 chunks
#define CATR 2176         // dt_proj(2048)+x_proj(32) rows padded to 17*128

typedef __attribute__((ext_vector_type(8))) short bf16x8;
typedef __attribute__((ext_vector_type(4))) float f32x4;

__device__ __forceinline__ short f2bf(float f) {
  union { float f; unsigned u; } a; a.f = f;
  return (short)((a.u + 0x7FFFu + ((a.u >> 16) & 1u)) >> 16);  // RNE
}
__device__ __forceinline__ float bf2f(short s) {
  union { unsigned u; float f; } a; a.u = ((unsigned)(unsigned short)s) << 16;
  return a.f;
}
// BK=32 bank swizzle (layer ring kernel)
__device__ __forceinline__ int hswz(int r) { return (r & 3) ^ ((r >> 2) & 3); }

// ---------------- batched f32 -> bf16 convert (layer weights only now) ----------------
struct CvtSeg { const float* s; short* d; unsigned n4; };
struct CvtBatch { CvtSeg seg[7]; unsigned tot4; };
__global__ __launch_bounds__(256) void cvt_all_k(CvtBatch b) {
  for (unsigned idx = blockIdx.x * 256 + threadIdx.x; idx < b.tot4;
       idx += gridDim.x * 256) {
    unsigned r = idx;
    int sg = 0;
    while (sg < 5 && r >= b.seg[sg].n4) { r -= b.seg[sg].n4; ++sg; }
    float4 v = ((const float4*)b.seg[sg].s)[r];
    short4 o;
    o.x = f2bf(v.x); o.y = f2bf(v.y); o.z = f2bf(v.z); o.w = f2bf(v.w);
    ((short4*)b.seg[sg].d)[r] = o;
  }
}

// ---------------- embedding gather ----------------
__global__ __launch_bounds__(256) void embed_k(const int* __restrict__ ids,
                                               const float* __restrict__ emb,
                                               float* __restrict__ x) {
  int s = blockIdx.x;
  int id = ids[s];
  const float4* src = (const float4*)(emb + (size_t)id * Dd);
  float4* dst = (float4*)(x + (size_t)s * Dd);
  dst[threadIdx.x] = src[threadIdx.x];
}

// ---------------- RMSNorm -> bf16 ----------------
__global__ __launch_bounds__(256) void rmsnorm_k(const float* __restrict__ x,
                                                 const float* __restrict__ w,
                                                 short* __restrict__ o) {
  int s = blockIdx.x, t = threadIdx.x;
  float4 v = ((const float4*)(x + (size_t)s * Dd))[t];
  float ss = v.x * v.x + v.y * v.y + v.z * v.z + v.w * v.w;
#pragma unroll
  for (int off = 32; off; off >>= 1) ss += __shfl_down(ss, off);
  __shared__ float red[4];
  if ((t & 63) == 0) red[t >> 6] = ss;
  __syncthreads();
  ss = red[0] + red[1] + red[2] + red[3];
  float rinv = rsqrtf(ss * (1.0f / Dd) + EPSf);
  float4 wv = ((const float4*)w)[t];
  short4 ov;
  ov.x = f2bf(v.x * rinv * wv.x);
  ov.y = f2bf(v.y * rinv * wv.y);
  ov.z = f2bf(v.z * rinv * wv.z);
  ov.w = f2bf(v.w * rinv * wv.w);
  ((short4*)(o + (size_t)s * Dd))[t] = ov;
}

// ============ 128^2 ring GEMM (layer GEMMs): BK=32, 4-deep ring, counted vmcnt ============
template <int BM, int BN, int WM, int WN, bool RESID, bool CAT>
__global__ __launch_bounds__(WM * WN * 64, 2) void gemm_ring(
    const short* __restrict__ A, const short* __restrict__ B,
    float* C, const float* resb, float* C2, int M, int N, int K, int nMt) {
  constexpr int NT = WM * WN * 64;
  constexpr int FM = BM / (WM * 16);
  constexpr int FN = BN / (WN * 16);
  constexpr int PA = BM * 4 / NT;
  constexpr int PB = BN * 4 / NT;
  static_assert(PA + PB == 4, "vmcnt literals assume 4 loads per stage");
  __shared__ short lds[4][(BM + BN) * 32];
  const int t = threadIdx.x;
  const int lane = t & 63;
  const int w = t >> 6;
  const int wm = w / WN, wn = w % WN;
  const int lr = lane & 15, l4 = lane >> 4;
  const int nwg = gridDim.x;
  const int chunk = nwg >> 3;
  const int wg = (blockIdx.x & 7) * chunk + (blockIdx.x >> 3);
  const int mi = wg % nMt, ni = wg / nMt;
  const size_t rowBase = (size_t)mi * BM, colBase = (size_t)ni * BN;

  const short* aSrc[PA]; int aOff[PA];
  const short* bSrc[PB]; int bOff[PB];
#pragma unroll
  for (int p = 0; p < PA; ++p) {
    int q = p * NT + t;
    int row = q >> 2, s = q & 3;
    aSrc[p] = A + (rowBase + row) * K + ((s ^ hswz(row)) << 3);
    aOff[p] = q * 8;
  }
#pragma unroll
  for (int p = 0; p < PB; ++p) {
    int q = p * NT + t;
    int row = q >> 2, s = q & 3;
    bSrc[p] = B + (colBase + row) * K + ((s ^ hswz(row)) << 3);
    bOff[p] = BM * 32 + q * 8;
  }
  auto stage = [&](int buf, int k0) {
#pragma unroll
    for (int p = 0; p < PA; ++p)
      __builtin_amdgcn_global_load_lds(
          (__attribute__((address_space(1))) unsigned int*)(aSrc[p] + k0),
          (__attribute__((address_space(3))) unsigned int*)(&lds[buf][aOff[p]]), 16, 0, 0);
#pragma unroll
    for (int p = 0; p < PB; ++p)
      __builtin_amdgcn_global_load_lds(
          (__attribute__((address_space(1))) unsigned int*)(bSrc[p] + k0),
          (__attribute__((address_space(3))) unsigned int*)(&lds[buf][bOff[p]]), 16, 0, 0);
  };

  f32x4 acc[FM][FN];
#pragma unroll
  for (int i = 0; i < FM; i++)
#pragma unroll
    for (int j = 0; j < FN; j++) acc[i][j] = f32x4{0.f, 0.f, 0.f, 0.f};

  const int KT = K >> 5;
  stage(0, 0); stage(1, 32); stage(2, 64);
  for (int kt = 0; kt < KT; ++kt) {
    const int rem = KT - 1 - kt;
    __builtin_amdgcn_sched_barrier(0);
    if (rem >= 2)      asm volatile("s_waitcnt vmcnt(8)" ::: "memory");
    else if (rem == 1) asm volatile("s_waitcnt vmcnt(4)" ::: "memory");
    else               asm volatile("s_waitcnt vmcnt(0)" ::: "memory");
    __builtin_amdgcn_sched_barrier(0);
    __builtin_amdgcn_s_barrier();
    __builtin_amdgcn_sched_barrier(0);
    if (kt + 3 < KT) stage((kt + 3) & 3, (kt + 3) << 5);
    const short* la = &lds[kt & 3][0];
    const short* lb = &lds[kt & 3][BM * 32];
    bf16x8 av[FM], bv[FN];
#pragma unroll
    for (int i = 0; i < FM; i++) {
      int r = wm * (FM * 16) + i * 16 + lr;
      av[i] = *(const bf16x8*)&la[r * 32 + ((l4 ^ hswz(r)) << 3)];
    }
#pragma unroll
    for (int j = 0; j < FN; j++) {
      int r = wn * (FN * 16) + j * 16 + lr;
      bv[j] = *(const bf16x8*)&lb[r * 32 + ((l4 ^ hswz(r)) << 3)];
    }
    __builtin_amdgcn_s_setprio(1);
#pragma unroll
    for (int i = 0; i < FM; i++)
#pragma unroll
      for (int j = 0; j < FN; j++)
        acc[i][j] = __builtin_amdgcn_mfma_f32_16x16x32_bf16(av[i], bv[j], acc[i][j], 0, 0, 0);
    __builtin_amdgcn_s_setprio(0);
  }
#pragma unroll
  for (int i = 0; i < FM; i++) {
#pragma unroll
    for (int j = 0; j < FN; j++) {
      size_t r0 = rowBase + wm * (FM * 16) + i * 16 + l4 * 4;
      size_t c = colBase + wn * (FN * 16) + j * 16 + lr;
#pragma unroll
      for (int rr = 0; rr < 4; rr++) {
        size_t r = r0 + rr;
        float v = acc[i][j][rr];
        if (CAT) {
          if (c < DIc) {
            float xv = v + resb[c];
            C[r * DIc + c] = fmaxf(xv, 0.f) + log1pf(__expf(-fabsf(xv)));
          } else if (c < DIc + 2 * Nn) {
            C2[r * (2 * Nn) + (c - DIc)] = v;
          }
        } else {
          size_t idx = r * N + c;
          if (RESID) v += resb[idx];
          C[idx] = v;
        }
      }
    }
  }
}

// ============ lm_head GEMM: 256^2, BK=64, 2-buf, B read as f32 + on-the-fly cvt ============
// A (bf16 activations): global_load_lds, pre-swizzled src (slot s^(r&7), R3/R7:
// 0 read conflicts). B (f32 weights): reg-staged T14 -- 8x float4 load, f2bf,
// swizzled ds_write_b128. Saves the separate 197MB cvt pass for lm_head.
// Schedule per iter kt (buf[cur] published): stageA(kt+1)->buf[nxt];
// loadB(kt+2)->regs; ds_read frags; vmcnt(12): B(kt+1) regs ready -> cvt +
// ds_write buf[nxt]; MFMA x64; vmcnt(8): A(kt+1) landed; lgkmcnt(0); barrier.
__global__ __launch_bounds__(512, 1) void gemm_lm(const short* __restrict__ A,
                                                  const float* __restrict__ Bf,
                                                  float* __restrict__ C,
                                                  int M, int N, int K, int nMt) {
  __shared__ short lds[2][512 * 64];   // [buf][A 256 rows | B 256 rows] * 64
  const int t = threadIdx.x;
  const int lane = t & 63;
  const int w = t >> 6;
  const int wm = w >> 2, wn = w & 3;
  const int lr = lane & 15, l4 = lane >> 4;
  const int nwg = gridDim.x, chunk = nwg >> 3;
  const int wg = (blockIdx.x & 7) * chunk + (blockIdx.x >> 3);
  const int mi = wg % nMt, ni = wg / nMt;
  const size_t rowBase = (size_t)mi * 256, colBase = (size_t)ni * 256;

  // A staging
  const short* aSrc[4]; int aOff[4];
#pragma unroll
  for (int p = 0; p < 4; ++p) {
    int q = p * 512 + t;
    int row = q >> 3, s = q & 7;
    aSrc[p] = A + (rowBase + row) * (size_t)K + ((s ^ (row & 7)) << 3);
    aOff[p] = q * 8;
  }
  auto stageA = [&](int buf, int k0) {
#pragma unroll
    for (int p = 0; p < 4; ++p)
      __builtin_amdgcn_global_load_lds(
          (__attribute__((address_space(1))) unsigned int*)(aSrc[p] + k0),
          (__attribute__((address_space(3))) unsigned int*)(&lds[buf][aOff[p]]), 16, 0, 0);
  };
  // B: each thread owns half a row (32 f32)
  const int brow = t >> 1, bhf = t & 1;
  const float* bSrc = Bf + (colBase + brow) * (size_t)K + bhf * 32;
  float4 s0[8], s1[8];
  auto loadB = [&](float4 (&dst)[8], int k0) {
    const float4* p4 = (const float4*)(bSrc + k0);
#pragma unroll
    for (int i = 0; i < 8; ++i) dst[i] = p4[i];
  };
  auto writeB = [&](float4 (&src)[8], int buf) {
    short* base = &lds[buf][256 * 64 + brow * 64];
#pragma unroll
    for (int i2 = 0; i2 < 4; ++i2) {
      float4 lo = src[i2 * 2], hi = src[i2 * 2 + 1];
      bf16x8 v;
      v[0] = f2bf(lo.x); v[1] = f2bf(lo.y); v[2] = f2bf(lo.z); v[3] = f2bf(lo.w);
      v[4] = f2bf(hi.x); v[5] = f2bf(hi.y); v[6] = f2bf(hi.z); v[7] = f2bf(hi.w);
      int slot = (4 * bhf + i2) ^ (brow & 7);
      *(bf16x8*)(base + slot * 8) = v;
    }
  };

  f32x4 acc[8][4];
#pragma unroll
  for (int i = 0; i < 8; i++)
#pragma unroll
    for (int j = 0; j < 4; j++) acc[i][j] = f32x4{0.f, 0.f, 0.f, 0.f};

  const int KT = K >> 6;   // 16 (even)
  // prologue: B0, B1 regs; A0 DMA; write B0; publish buf0
  loadB(s0, 0);
  loadB(s1, 64);
  stageA(0, 0);
  __builtin_amdgcn_sched_barrier(0);
  asm volatile("s_waitcnt vmcnt(12)" ::: "memory");   // B0 ready
  __builtin_amdgcn_sched_barrier(0);
  writeB(s0, 0);
  __builtin_amdgcn_sched_barrier(0);
  asm volatile("s_waitcnt vmcnt(8) lgkmcnt(0)" ::: "memory");  // A0 landed, writes visible
  __builtin_amdgcn_sched_barrier(0);
  __builtin_amdgcn_s_barrier();

  auto iter = [&](int kt, float4 (&bW)[8], float4 (&bL)[8]) {
    const int cur = kt & 1, nxt = cur ^ 1;
    const int rem = KT - 1 - kt;
    if (rem >= 1) stageA(nxt, (kt + 1) << 6);
    if (rem >= 2) loadB(bL, (kt + 2) << 6);
    const short* la = &lds[cur][0];
    const short* lb = &lds[cur][256 * 64];
    bf16x8 av[8][2], bv[4][2];
#pragma unroll
    for (int i = 0; i < 8; ++i)
#pragma unroll
      for (int kq = 0; kq < 2; ++kq) {
        int r = wm * 128 + i * 16 + lr;
        int sidx = kq * 4 + l4;
        av[i][kq] = *(const bf16x8*)&la[r * 64 + ((sidx ^ (r & 7)) << 3)];
      }
#pragma unroll
    for (int j = 0; j < 4; ++j)
#pragma unroll
      for (int kq = 0; kq < 2; ++kq) {
        int r = wn * 64 + j * 16 + lr;
        int sidx = kq * 4 + l4;
        bv[j][kq] = *(const bf16x8*)&lb[r * 64 + ((sidx ^ (r & 7)) << 3)];
      }
    if (rem >= 1) {
      __builtin_amdgcn_sched_barrier(0);
      if (rem >= 2) asm volatile("s_waitcnt vmcnt(12)" ::: "memory");  // B(kt+1) regs
      else          asm volatile("s_waitcnt vmcnt(4)" ::: "memory");
      __builtin_amdgcn_sched_barrier(0);
      writeB(bW, nxt);
    }
    __builtin_amdgcn_s_setprio(1);
#pragma unroll
    for (int kq = 0; kq < 2; ++kq)
#pragma unroll
      for (int i = 0; i < 8; ++i)
#pragma unroll
        for (int j = 0; j < 4; ++j)
          acc[i][j] = __builtin_amdgcn_mfma_f32_16x16x32_bf16(av[i][kq], bv[j][kq], acc[i][j], 0, 0, 0);
    __builtin_amdgcn_s_setprio(0);
    if (rem >= 1) {
      __builtin_amdgcn_sched_barrier(0);
      if (rem >= 2) asm volatile("s_waitcnt vmcnt(8) lgkmcnt(0)" ::: "memory");  // A(kt+1)
      else          asm volatile("s_waitcnt vmcnt(0) lgkmcnt(0)" ::: "memory");
      __builtin_amdgcn_sched_barrier(0);
      __builtin_amdgcn_s_barrier();
    }
  };
  for (int kt = 0; kt < KT; kt += 2) {
    iter(kt, s1, s0);       // B(kt+1) is odd -> s1; load B(kt+2) into s0
    iter(kt + 1, s0, s1);   // B(kt+2) even -> s0; load B(kt+3) into s1
  }
  // epilogue (C/D layout: col=lane&15, row=4*(lane>>4)+reg)
#pragma unroll
  for (int i = 0; i < 8; i++) {
#pragma unroll
    for (int j = 0; j < 4; j++) {
      size_t r0 = rowBase + wm * 128 + i * 16 + l4 * 4;
      size_t c = colBase + wn * 64 + j * 16 + lr;
#pragma unroll
      for (int rr = 0; rr < 4; rr++)
        C[(r0 + rr) * N + c] = acc[i][j][rr];
    }
  }
}

// ---------------- depthwise causal conv1d (K=4) + bias + SiLU -> bf16, x4 vec ----------------
__global__ __launch_bounds__(256) void conv_silu_k(const float* __restrict__ xz,
                                                   const float* __restrict__ cw,
                                                   const float* __restrict__ cb,
                                                   short* __restrict__ xiC) {
  int idx = blockIdx.x * 256 + threadIdx.x;  // over S*DI/4
  int s = idx / (DIc / 4), c4 = idx - s * (DIc / 4);
  const float4* xz4 = (const float4*)xz;
  const size_t rstride = 2 * DIc / 4;
  float4 zero = {0.f, 0.f, 0.f, 0.f};
  float4 x0 = (s >= 3) ? xz4[(size_t)(s - 3) * rstride + c4] : zero;
  float4 x1 = (s >= 2) ? xz4[(size_t)(s - 2) * rstride + c4] : zero;
  float4 x2 = (s >= 1) ? xz4[(size_t)(s - 1) * rstride + c4] : zero;
  float4 x3 = xz4[(size_t)s * rstride + c4];
  float4 cbv = ((const float4*)cb)[c4];
  short4 ov;
  float xs[4][4] = {{x0.x, x1.x, x2.x, x3.x}, {x0.y, x1.y, x2.y, x3.y},
                    {x0.z, x1.z, x2.z, x3.z}, {x0.w, x1.w, x2.w, x3.w}};
  float cbs[4] = {cbv.x, cbv.y, cbv.z, cbv.w};
  short os[4];
#pragma unroll
  for (int j = 0; j < 4; j++) {
    float4 wv = ((const float4*)cw)[c4 * 4 + j];
    float acc = cbs[j] + wv.x * xs[j][0] + wv.y * xs[j][1] + wv.z * xs[j][2] + wv.w * xs[j][3];
    os[j] = f2bf(acc / (1.f + __expf(-acc)));
  }
  ov.x = os[0]; ov.y = os[1]; ov.z = os[2]; ov.w = os[3];
  ((short4*)xiC)[idx] = ov;
}

// ---------------- scan pass 1 ----------------
__global__ __launch_bounds__(256) void scan_pass1(const float* __restrict__ dt,
                                                  const short* __restrict__ u,
                                                  const float* __restrict__ bc,
                                                  const float* __restrict__ alog,
                                                  float* __restrict__ Ap,
                                                  float* __restrict__ Hl) {
  const int j = blockIdx.x;
  const int d = blockIdx.y * 256 + threadIdx.x;
  __shared__ float sB[LCH][Nn];
  for (int q = threadIdx.x; q < LCH * Nn; q += 256) {
    int tt = q >> 4, n = q & 15;
    sB[tt][n] = bc[(size_t)(j * LCH + tt) * 32 + n];
  }
  __syncthreads();
  float Ar[Nn], h[Nn], ap[Nn];
#pragma unroll
  for (int n = 0; n < Nn; n++) {
    Ar[n] = -__expf(alog[d * Nn + n]); h[n] = 0.f; ap[n] = 1.f;
  }
  const int t0 = j * LCH;
  for (int tt = 0; tt < LCH; tt++) {
    size_t gi = (size_t)(t0 + tt) * DIc + d;
    float dtv = dt[gi];
    float uv = bf2f(u[gi]);
    float dtu = dtv * uv;
#pragma unroll
    for (int n = 0; n < Nn; n++) {
      float a = __expf(dtv * Ar[n]);
      h[n] = a * h[n] + dtu * sB[tt][n];
      ap[n] *= a;
    }
  }
  size_t base = ((size_t)j * DIc + d) * Nn;
#pragma unroll
  for (int n = 0; n < Nn; n++) { Ap[base + n] = ap[n]; Hl[base + n] = h[n]; }
}

// ---------------- scan combine ----------------
__global__ __launch_bounds__(256) void scan_combine(const float* __restrict__ Ap,
                                                    const float* __restrict__ Hl,
                                                    float* __restrict__ Hi) {
  int idx = blockIdx.x * 256 + threadIdx.x;
  float h = 0.f;
  for (int j = 0; j < NCHc; j++) {
    size_t o = (size_t)j * DIc * Nn + idx;
    Hi[o] = h;
    h = Ap[o] * h + Hl[o];
  }
}

// ---------------- scan pass 2 ----------------
__global__ __launch_bounds__(256) void scan_pass2(const float* __restrict__ dt,
                                                  const short* __restrict__ u,
                                                  const float* __restrict__ bc,
                                                  const float* __restrict__ alog,
                                                  const float* __restrict__ Hinit,
                                                  const float* __restrict__ Dp,
                                                  const float* __restrict__ xz,
                                                  short* __restrict__ y) {
  const int j = blockIdx.x;
  const int d = blockIdx.y * 256 + threadIdx.x;
  __shared__ float sB[LCH][Nn], sC[LCH][Nn];
  for (int q = threadIdx.x; q < LCH * Nn; q += 256) {
    int tt = q >> 4, n = q & 15;
    size_t r = (size_t)(j * LCH + tt) * 32;
    sB[tt][n] = bc[r + n];
    sC[tt][n] = bc[r + 16 + n];
  }
  __syncthreads();
  float Ar[Nn], h[Nn];
  size_t hb = ((size_t)j * DIc + d) * Nn;
#pragma unroll
  for (int n = 0; n < Nn; n++) {
    Ar[n] = -__expf(alog[d * Nn + n]); h[n] = Hinit[hb + n];
  }
  float dp = Dp[d];
  const int t0 = j * LCH;
  for (int tt = 0; tt < LCH; tt++) {
    size_t gi = (size_t)(t0 + tt) * DIc + d;
    float dtv = dt[gi];
    float uv = bf2f(u[gi]);
    float dtu = dtv * uv;
    float yv = dp * uv;
#pragma unroll
    for (int n = 0; n < Nn; n++) {
      float a = __expf(dtv * Ar[n]);
      h[n] = a * h[n] + dtu * sB[tt][n];
      yv += h[n] * sC[tt][n];
    }
    float zv = xz[(size_t)(t0 + tt) * (2 * DIc) + DIc + d];
    float sz = zv / (1.f + __expf(-zv));
    y[gi] = f2bf(yv * sz);
  }
}

// ---------------- host orchestration ----------------
extern "C" void kernel_launch(void* const* d_in, const int* in_sizes, int n_in,
                              void* d_out, int out_size, void* d_ws, size_t ws_size,
                              hipStream_t stream) {
  (void)in_sizes; (void)n_in; (void)out_size; (void)ws_size;
  const int* ids = (const int*)d_in[0];
  const float* emb = (const float*)d_in[1];
  const float* in_proj_w = (const float*)d_in[2];
  const float* conv_w = (const float*)d_in[3];
  const float* conv_b = (const float*)d_in[4];
  const float* x_proj_w = (const float*)d_in[5];
  const float* dt_proj_w = (const float*)d_in[6];
  const float* dt_proj_b = (const float*)d_in[7];
  const float* A_log = (const float*)d_in[8];
  const float* D_param = (const float*)d_in[9];
  const float* out_proj_w = (const float*)d_in[10];
  const float* norm_w = (const float*)d_in[11];
  const float* norm_f_w = (const float*)d_in[12];
  const float* lm_head_w = (const float*)d_in[13];
  float* logits = (float*)d_out;

  // lm_head-phase-live buffers in d_ws; dead-before-final-GEMM scratch in d_out.
  char* ws = (char*)d_ws;
  size_t woff = 0;
  auto walloc = [&](size_t bytes) { void* p = ws + woff; woff += (bytes + 255) & ~(size_t)255; return p; };
  float* x     = (float*)walloc((size_t)Ss * Dd * 4);
  short* xfbf  = (short*)walloc((size_t)Ss * Dd * 2);

  char* sc = (char*)d_out;
  size_t soff = 0;
  auto salloc = [&](size_t bytes) { void* p = sc + soff; soff += (bytes + 255) & ~(size_t)255; return p; };
  float* xz   = (float*)salloc((size_t)Ss * 2 * DIc * 4);
  float* dtb  = (float*)salloc((size_t)Ss * DIc * 4);
  float* bc   = (float*)salloc((size_t)Ss * 32 * 4);
  float* Ap   = (float*)salloc((size_t)NCHc * DIc * Nn * 4);
  float* Hl   = (float*)salloc((size_t)NCHc * DIc * Nn * 4);
  float* Hi   = (float*)salloc((size_t)NCHc * DIc * Nn * 4);
  short* hbf  = (short*)salloc((size_t)Ss * Dd * 2);
  short* xiC  = (short*)salloc((size_t)Ss * DIc * 2);
  short* ybf  = (short*)salloc((size_t)Ss * DIc * 2);
  short* w_in = (short*)salloc((size_t)NLay * 2 * DIc * Dd * 2);
  short* w_cat= (short*)salloc((size_t)NLay * CATR * DIc * 2);
  short* w_out= (short*)salloc((size_t)NLay * Dd * DIc * 2);

  // layer weights only (lm_head is consumed as f32 directly by gemm_lm)
  CvtBatch cb2{};
  unsigned tot = 0;
  auto addseg = [&](int i, const float* s, short* d, size_t n) {
    cb2.seg[i].s = s; cb2.seg[i].d = d; cb2.seg[i].n4 = (unsigned)(n / 4);
    tot += (unsigned)(n / 4);
  };
  addseg(0, in_proj_w, w_in, (size_t)NLay * 2 * DIc * Dd);
  addseg(1, out_proj_w, w_out, (size_t)NLay * Dd * DIc);
  addseg(2, dt_proj_w, w_cat, (size_t)DIc * DIc);
  addseg(3, x_proj_w, w_cat + (size_t)DIc * DIc, (size_t)2 * Nn * DIc);
  addseg(4, dt_proj_w + (size_t)DIc * DIc, w_cat + (size_t)CATR * DIc, (size_t)DIc * DIc);
  addseg(5, x_proj_w + (size_t)2 * Nn * DIc,
         w_cat + (size_t)CATR * DIc + (size_t)DIc * DIc, (size_t)2 * Nn * DIc);
  cb2.tot4 = tot;
  cvt_all_k<<<dim3(2048), dim3(256), 0, stream>>>(cb2);

  embed_k<<<dim3(Ss), dim3(256), 0, stream>>>(ids, emb, x);

  for (int l = 0; l < NLay; l++) {
    rmsnorm_k<<<dim3(Ss), dim3(256), 0, stream>>>(x, norm_w + (size_t)l * Dd, hbf);
    gemm_ring<128, 128, 2, 2, false, false><<<dim3(512), dim3(256), 0, stream>>>(
        hbf, w_in + (size_t)l * 2 * DIc * Dd, xz, nullptr, nullptr, Ss, 2 * DIc, Dd, 16);
    conv_silu_k<<<dim3(Ss * DIc / 4 / 256), dim3(256), 0, stream>>>(
        xz, conv_w + (size_t)l * DIc * Kc, conv_b + (size_t)l * DIc, xiC);
    gemm_ring<128, 128, 2, 2, false, true><<<dim3(272), dim3(256), 0, stream>>>(
        xiC, w_cat + (size_t)l * CATR * DIc, dtb, dt_proj_b + (size_t)l * DIc, bc,
        Ss, CATR, DIc, 16);
    scan_pass1<<<dim3(NCHc, DIc / 256), dim3(256), 0, stream>>>(
        dtb, xiC, bc, A_log + (size_t)l * DIc * Nn, Ap, Hl);
    scan_combine<<<dim3(DIc * Nn / 256), dim3(256), 0, stream>>>(Ap, Hl, Hi);
    scan_pass2<<<dim3(NCHc, DIc / 256), dim3(256), 0, stream>>>(
        dtb, xiC, bc, A_log + (size_t)l * DIc * Nn, Hi,
        D_param + (size_t)l * DIc, xz, ybf);
    gemm_ring<128, 128, 2, 2, true, false><<<dim3(128), dim3(256), 0, stream>>>(
        ybf, w_out + (size_t)l * Dd * DIc, x, x, nullptr, Ss, Dd, DIc, 16);
  }

  rmsnorm_k<<<dim3(Ss), dim3(256), 0, stream>>>(x, norm_f_w, xfbf);
  // lm_head: 8 x 125 = 1000 blocks, f32-B direct kernel
  gemm_lm<<<dim3(1000), dim3(512), 0, stream>>>(xfbf, lm_head_w, logits, Ss, Vv, Dd, 8);
}

// Round 10
// 641.544 us; speedup vs baseline: 2.0352x; 2.0352x over previous
//
#include <hip/hip_runtime.h>
#include <hip/hip_bf16.h>
#include <stdint.h>
#include <stddef.h>

// ---- model dims ----
#define Vv   32000
#define Dd   1024
#define NLay 2
#define Ss   2048
#define Nn   16
#define Kc   4
#define DIc  2048
#define EPSf 1e-5f
#define LCH  32
#define NCHc (Ss / LCH)   // 64 chunks
#define CATR 2176         // dt_proj(2048)+x_proj(32) rows padded to 17*128

typedef __attribute__((ext_vector_type(8))) short bf16x8;
typedef __attribute__((ext_vector_type(4))) float f32x4;

__device__ __forceinline__ short f2bf(float f) {
  union { float f; unsigned u; } a; a.f = f;
  return (short)((a.u + 0x7FFFu + ((a.u >> 16) & 1u)) >> 16);  // RNE
}
__device__ __forceinline__ float bf2f(short s) {
  union { unsigned u; float f; } a; a.u = ((unsigned)(unsigned short)s) << 16;
  return a.f;
}
// BK=32 bank swizzle (layer ring kernel)
__device__ __forceinline__ int hswz(int r) { return (r & 3) ^ ((r >> 2) & 3); }

// ---------------- batched f32 -> bf16 convert (all weights, 1 launch) ----------------
struct CvtSeg { const float* s; short* d; unsigned n4; };
struct CvtBatch { CvtSeg seg[7]; unsigned tot4; };
__global__ __launch_bounds__(256) void cvt_all_k(CvtBatch b) {
  for (unsigned idx = blockIdx.x * 256 + threadIdx.x; idx < b.tot4;
       idx += gridDim.x * 256) {
    unsigned r = idx;
    int sg = 0;
    while (sg < 6 && r >= b.seg[sg].n4) { r -= b.seg[sg].n4; ++sg; }
    float4 v = ((const float4*)b.seg[sg].s)[r];
    short4 o;
    o.x = f2bf(v.x); o.y = f2bf(v.y); o.z = f2bf(v.z); o.w = f2bf(v.w);
    ((short4*)b.seg[sg].d)[r] = o;
  }
}

// ---------------- embedding gather + layer-0 RMSNorm (fused) ----------------
__global__ __launch_bounds__(256) void embed_norm_k(const int* __restrict__ ids,
                                                    const float* __restrict__ emb,
                                                    const float* __restrict__ w,
                                                    float* __restrict__ x,
                                                    short* __restrict__ o) {
  int s = blockIdx.x, t = threadIdx.x;
  int id = ids[s];
  float4 v = ((const float4*)(emb + (size_t)id * Dd))[t];
  ((float4*)(x + (size_t)s * Dd))[t] = v;     // residual stream
  float ss = v.x * v.x + v.y * v.y + v.z * v.z + v.w * v.w;
#pragma unroll
  for (int off = 32; off; off >>= 1) ss += __shfl_down(ss, off);
  __shared__ float red[4];
  if ((t & 63) == 0) red[t >> 6] = ss;
  __syncthreads();
  ss = red[0] + red[1] + red[2] + red[3];
  float rinv = rsqrtf(ss * (1.0f / Dd) + EPSf);
  float4 wv = ((const float4*)w)[t];
  short4 ov;
  ov.x = f2bf(v.x * rinv * wv.x);
  ov.y = f2bf(v.y * rinv * wv.y);
  ov.z = f2bf(v.z * rinv * wv.z);
  ov.w = f2bf(v.w * rinv * wv.w);
  ((short4*)(o + (size_t)s * Dd))[t] = ov;
}

// ---------------- RMSNorm -> bf16 ----------------
__global__ __launch_bounds__(256) void rmsnorm_k(const float* __restrict__ x,
                                                 const float* __restrict__ w,
                                                 short* __restrict__ o) {
  int s = blockIdx.x, t = threadIdx.x;
  float4 v = ((const float4*)(x + (size_t)s * Dd))[t];
  float ss = v.x * v.x + v.y * v.y + v.z * v.z + v.w * v.w;
#pragma unroll
  for (int off = 32; off; off >>= 1) ss += __shfl_down(ss, off);
  __shared__ float red[4];
  if ((t & 63) == 0) red[t >> 6] = ss;
  __syncthreads();
  ss = red[0] + red[1] + red[2] + red[3];
  float rinv = rsqrtf(ss * (1.0f / Dd) + EPSf);
  float4 wv = ((const float4*)w)[t];
  short4 ov;
  ov.x = f2bf(v.x * rinv * wv.x);
  ov.y = f2bf(v.y * rinv * wv.y);
  ov.z = f2bf(v.z * rinv * wv.z);
  ov.w = f2bf(v.w * rinv * wv.w);
  ((short4*)(o + (size_t)s * Dd))[t] = ov;
}

// ============ 128^2 ring GEMM (layer GEMMs): BK=32, 4-deep ring, counted vmcnt ============
template <int BM, int BN, int WM, int WN, bool RESID, bool CAT>
__global__ __launch_bounds__(WM * WN * 64, 2) void gemm_ring(
    const short* __restrict__ A, const short* __restrict__ B,
    float* C, const float* resb, float* C2, int M, int N, int K, int nMt) {
  constexpr int NT = WM * WN * 64;
  constexpr int FM = BM / (WM * 16);
  constexpr int FN = BN / (WN * 16);
  constexpr int PA = BM * 4 / NT;
  constexpr int PB = BN * 4 / NT;
  static_assert(PA + PB == 4, "vmcnt literals assume 4 loads per stage");
  __shared__ short lds[4][(BM + BN) * 32];
  const int t = threadIdx.x;
  const int lane = t & 63;
  const int w = t >> 6;
  const int wm = w / WN, wn = w % WN;
  const int lr = lane & 15, l4 = lane >> 4;
  const int nwg = gridDim.x;
  const int chunk = nwg >> 3;
  const int wg = (blockIdx.x & 7) * chunk + (blockIdx.x >> 3);
  const int mi = wg % nMt, ni = wg / nMt;
  const size_t rowBase = (size_t)mi * BM, colBase = (size_t)ni * BN;

  const short* aSrc[PA]; int aOff[PA];
  const short* bSrc[PB]; int bOff[PB];
#pragma unroll
  for (int p = 0; p < PA; ++p) {
    int q = p * NT + t;
    int row = q >> 2, s = q & 3;
    aSrc[p] = A + (rowBase + row) * K + ((s ^ hswz(row)) << 3);
    aOff[p] = q * 8;
  }
#pragma unroll
  for (int p = 0; p < PB; ++p) {
    int q = p * NT + t;
    int row = q >> 2, s = q & 3;
    bSrc[p] = B + (colBase + row) * K + ((s ^ hswz(row)) << 3);
    bOff[p] = BM * 32 + q * 8;
  }
  auto stage = [&](int buf, int k0) {
#pragma unroll
    for (int p = 0; p < PA; ++p)
      __builtin_amdgcn_global_load_lds(
          (__attribute__((address_space(1))) unsigned int*)(aSrc[p] + k0),
          (__attribute__((address_space(3))) unsigned int*)(&lds[buf][aOff[p]]), 16, 0, 0);
#pragma unroll
    for (int p = 0; p < PB; ++p)
      __builtin_amdgcn_global_load_lds(
          (__attribute__((address_space(1))) unsigned int*)(bSrc[p] + k0),
          (__attribute__((address_space(3))) unsigned int*)(&lds[buf][bOff[p]]), 16, 0, 0);
  };

  f32x4 acc[FM][FN];
#pragma unroll
  for (int i = 0; i < FM; i++)
#pragma unroll
    for (int j = 0; j < FN; j++) acc[i][j] = f32x4{0.f, 0.f, 0.f, 0.f};

  const int KT = K >> 5;
  stage(0, 0); stage(1, 32); stage(2, 64);
  for (int kt = 0; kt < KT; ++kt) {
    const int rem = KT - 1 - kt;
    __builtin_amdgcn_sched_barrier(0);
    if (rem >= 2)      asm volatile("s_waitcnt vmcnt(8)" ::: "memory");
    else if (rem == 1) asm volatile("s_waitcnt vmcnt(4)" ::: "memory");
    else               asm volatile("s_waitcnt vmcnt(0)" ::: "memory");
    __builtin_amdgcn_sched_barrier(0);
    __builtin_amdgcn_s_barrier();
    __builtin_amdgcn_sched_barrier(0);
    if (kt + 3 < KT) stage((kt + 3) & 3, (kt + 3) << 5);
    const short* la = &lds[kt & 3][0];
    const short* lb = &lds[kt & 3][BM * 32];
    bf16x8 av[FM], bv[FN];
#pragma unroll
    for (int i = 0; i < FM; i++) {
      int r = wm * (FM * 16) + i * 16 + lr;
      av[i] = *(const bf16x8*)&la[r * 32 + ((l4 ^ hswz(r)) << 3)];
    }
#pragma unroll
    for (int j = 0; j < FN; j++) {
      int r = wn * (FN * 16) + j * 16 + lr;
      bv[j] = *(const bf16x8*)&lb[r * 32 + ((l4 ^ hswz(r)) << 3)];
    }
    __builtin_amdgcn_s_setprio(1);
#pragma unroll
    for (int i = 0; i < FM; i++)
#pragma unroll
      for (int j = 0; j < FN; j++)
        acc[i][j] = __builtin_amdgcn_mfma_f32_16x16x32_bf16(av[i], bv[j], acc[i][j], 0, 0, 0);
    __builtin_amdgcn_s_setprio(0);
  }
#pragma unroll
  for (int i = 0; i < FM; i++) {
#pragma unroll
    for (int j = 0; j < FN; j++) {
      size_t r0 = rowBase + wm * (FM * 16) + i * 16 + l4 * 4;
      size_t c = colBase + wn * (FN * 16) + j * 16 + lr;
#pragma unroll
      for (int rr = 0; rr < 4; rr++) {
        size_t r = r0 + rr;
        float v = acc[i][j][rr];
        if (CAT) {
          if (c < DIc) {
            float xv = v + resb[c];
            C[r * DIc + c] = fmaxf(xv, 0.f) + log1pf(__expf(-fabsf(xv)));
          } else if (c < DIc + 2 * Nn) {
            C2[r * (2 * Nn) + (c - DIc)] = v;
          }
        } else {
          size_t idx = r * N + c;
          if (RESID) v += resb[idx];
          C[idx] = v;
        }
      }
    }
  }
}

// ============ 256^2 lm_head GEMM (round-3 verbatim: best measured, 160us, 0 conflicts) ============
// 512 thr = 8 waves (2M x 4N); BK=64; LDS 128KB double-buffered.
// Swizzle: 16B slot s of row r holds global k-slot (s ^ (r&7)) -- pre-swizzled
// global source keeps global_load_lds dest linear; ds_read applies same XOR.
// Pipeline: stage(kt+1) issued at top of kt's compute; single __syncthreads()
// (vmcnt drain) per K-tile lands after ~64 MFMAs of slack.
__global__ __launch_bounds__(512, 2) void gemm256(const short* __restrict__ A,
                                                  const short* __restrict__ B,
                                                  float* __restrict__ C,
                                                  int M, int N, int K, int nMt) {
  __shared__ short lds[2][2][256 * 64];  // [buf][0=A,1=B][row*64 + k]
  const int t = threadIdx.x;
  const int lane = t & 63;
  const int w = t >> 6;
  const int wm = w >> 2, wn = w & 3;
  const int lr = lane & 15, l4 = lane >> 4;
  const int nwg = gridDim.x;
  const int chunk = nwg >> 3;
  const int wg = (blockIdx.x & 7) * chunk + (blockIdx.x >> 3);
  const int mi = wg % nMt, ni = wg / nMt;
  const size_t rowBase = (size_t)mi * 256, colBase = (size_t)ni * 256;

  const short* aSrc[4]; const short* bSrc[4];
  int ldsOff[4];
#pragma unroll
  for (int p = 0; p < 4; ++p) {
    int q = p * 512 + t;
    int row = q >> 3, s = q & 7;
    int ks = (s ^ (row & 7)) * 8;
    aSrc[p] = A + (rowBase + row) * K + ks;
    bSrc[p] = B + (colBase + row) * K + ks;
    ldsOff[p] = q * 8;
  }
  auto stage = [&](int buf, int k0) {
#pragma unroll
    for (int p = 0; p < 4; ++p)
      __builtin_amdgcn_global_load_lds(
          (__attribute__((address_space(1))) unsigned int*)(aSrc[p] + k0),
          (__attribute__((address_space(3))) unsigned int*)(&lds[buf][0][ldsOff[p]]), 16, 0, 0);
#pragma unroll
    for (int p = 0; p < 4; ++p)
      __builtin_amdgcn_global_load_lds(
          (__attribute__((address_space(1))) unsigned int*)(bSrc[p] + k0),
          (__attribute__((address_space(3))) unsigned int*)(&lds[buf][1][ldsOff[p]]), 16, 0, 0);
  };

  f32x4 acc[8][4];
#pragma unroll
  for (int i = 0; i < 8; i++)
#pragma unroll
    for (int j = 0; j < 4; j++) acc[i][j] = f32x4{0.f, 0.f, 0.f, 0.f};

  stage(0, 0);
  const int KT = K >> 6;
  for (int kt = 0; kt < KT; ++kt) {
    const int cur = kt & 1;
    __syncthreads();  // drains vmcnt(0): stage(kt) done; buf[cur^1] free
    bf16x8 a0[4][2], b0[4][2];
#pragma unroll
    for (int i = 0; i < 4; i++)
#pragma unroll
      for (int kq = 0; kq < 2; kq++) {
        int r = wm * 128 + i * 16 + lr;
        int ks = kq * 4 + l4;
        a0[i][kq] = *(const bf16x8*)&lds[cur][0][r * 64 + ((ks ^ (r & 7)) << 3)];
      }
#pragma unroll
    for (int j = 0; j < 4; j++)
#pragma unroll
      for (int kq = 0; kq < 2; kq++) {
        int r = wn * 64 + j * 16 + lr;
        int ks = kq * 4 + l4;
        b0[j][kq] = *(const bf16x8*)&lds[cur][1][r * 64 + ((ks ^ (r & 7)) << 3)];
      }
    if (kt + 1 < KT) stage(cur ^ 1, (kt + 1) << 6);
    __builtin_amdgcn_s_setprio(1);
#pragma unroll
    for (int i = 0; i < 4; i++)
#pragma unroll
      for (int j = 0; j < 4; j++)
#pragma unroll
        for (int kq = 0; kq < 2; kq++)
          acc[i][j] = __builtin_amdgcn_mfma_f32_16x16x32_bf16(a0[i][kq], b0[j][kq], acc[i][j], 0, 0, 0);
    __builtin_amdgcn_s_setprio(0);
    bf16x8 a1[4][2];
#pragma unroll
    for (int i = 0; i < 4; i++)
#pragma unroll
      for (int kq = 0; kq < 2; kq++) {
        int r = wm * 128 + 64 + i * 16 + lr;
        int ks = kq * 4 + l4;
        a1[i][kq] = *(const bf16x8*)&lds[cur][0][r * 64 + ((ks ^ (r & 7)) << 3)];
      }
    __builtin_amdgcn_s_setprio(1);
#pragma unroll
    for (int i = 0; i < 4; i++)
#pragma unroll
      for (int j = 0; j < 4; j++)
#pragma unroll
        for (int kq = 0; kq < 2; kq++)
          acc[i + 4][j] = __builtin_amdgcn_mfma_f32_16x16x32_bf16(a1[i][kq], b0[j][kq], acc[i + 4][j], 0, 0, 0);
    __builtin_amdgcn_s_setprio(0);
  }
#pragma unroll
  for (int i = 0; i < 8; i++) {
#pragma unroll
    for (int j = 0; j < 4; j++) {
      size_t r0 = rowBase + wm * 128 + i * 16 + l4 * 4;
      size_t c = colBase + wn * 64 + j * 16 + lr;
#pragma unroll
      for (int rr = 0; rr < 4; rr++)
        C[(r0 + rr) * N + c] = acc[i][j][rr];
    }
  }
}

// ---------------- depthwise causal conv1d (K=4) + bias + SiLU -> bf16, x4 vec ----------------
__global__ __launch_bounds__(256) void conv_silu_k(const float* __restrict__ xz,
                                                   const float* __restrict__ cw,
                                                   const float* __restrict__ cb,
                                                   short* __restrict__ xiC) {
  int idx = blockIdx.x * 256 + threadIdx.x;  // over S*DI/4
  int s = idx / (DIc / 4), c4 = idx - s * (DIc / 4);
  const float4* xz4 = (const float4*)xz;
  const size_t rstride = 2 * DIc / 4;
  float4 zero = {0.f, 0.f, 0.f, 0.f};
  float4 x0 = (s >= 3) ? xz4[(size_t)(s - 3) * rstride + c4] : zero;
  float4 x1 = (s >= 2) ? xz4[(size_t)(s - 2) * rstride + c4] : zero;
  float4 x2 = (s >= 1) ? xz4[(size_t)(s - 1) * rstride + c4] : zero;
  float4 x3 = xz4[(size_t)s * rstride + c4];
  float4 cbv = ((const float4*)cb)[c4];
  short4 ov;
  float xs[4][4] = {{x0.x, x1.x, x2.x, x3.x}, {x0.y, x1.y, x2.y, x3.y},
                    {x0.z, x1.z, x2.z, x3.z}, {x0.w, x1.w, x2.w, x3.w}};
  float cbs[4] = {cbv.x, cbv.y, cbv.z, cbv.w};
  short os[4];
#pragma unroll
  for (int j = 0; j < 4; j++) {
    float4 wv = ((const float4*)cw)[c4 * 4 + j];
    float acc = cbs[j] + wv.x * xs[j][0] + wv.y * xs[j][1] + wv.z * xs[j][2] + wv.w * xs[j][3];
    os[j] = f2bf(acc / (1.f + __expf(-acc)));
  }
  ov.x = os[0]; ov.y = os[1]; ov.z = os[2]; ov.w = os[3];
  ((short4*)xiC)[idx] = ov;
}

// ---------------- scan pass 1 ----------------
__global__ __launch_bounds__(256) void scan_pass1(const float* __restrict__ dt,
                                                  const short* __restrict__ u,
                                                  const float* __restrict__ bc,
                                                  const float* __restrict__ alog,
                                                  float* __restrict__ Ap,
                                                  float* __restrict__ Hl) {
  const int j = blockIdx.x;
  const int d = blockIdx.y * 256 + threadIdx.x;
  __shared__ float sB[LCH][Nn];
  for (int q = threadIdx.x; q < LCH * Nn; q += 256) {
    int tt = q >> 4, n = q & 15;
    sB[tt][n] = bc[(size_t)(j * LCH + tt) * 32 + n];
  }
  __syncthreads();
  float Ar[Nn], h[Nn], ap[Nn];
#pragma unroll
  for (int n = 0; n < Nn; n++) {
    Ar[n] = -__expf(alog[d * Nn + n]); h[n] = 0.f; ap[n] = 1.f;
  }
  const int t0 = j * LCH;
  for (int tt = 0; tt < LCH; tt++) {
    size_t gi = (size_t)(t0 + tt) * DIc + d;
    float dtv = dt[gi];
    float uv = bf2f(u[gi]);
    float dtu = dtv * uv;
#pragma unroll
    for (int n = 0; n < Nn; n++) {
      float a = __expf(dtv * Ar[n]);
      h[n] = a * h[n] + dtu * sB[tt][n];
      ap[n] *= a;
    }
  }
  size_t base = ((size_t)j * DIc + d) * Nn;
#pragma unroll
  for (int n = 0; n < Nn; n++) { Ap[base + n] = ap[n]; Hl[base + n] = h[n]; }
}

// ---------------- scan combine ----------------
__global__ __launch_bounds__(256) void scan_combine(const float* __restrict__ Ap,
                                                    const float* __restrict__ Hl,
                                                    float* __restrict__ Hi) {
  int idx = blockIdx.x * 256 + threadIdx.x;
  float h = 0.f;
  for (int j = 0; j < NCHc; j++) {
    size_t o = (size_t)j * DIc * Nn + idx;
    Hi[o] = h;
    h = Ap[o] * h + Hl[o];
  }
}

// ---------------- scan pass 2 ----------------
__global__ __launch_bounds__(256) void scan_pass2(const float* __restrict__ dt,
                                                  const short* __restrict__ u,
                                                  const float* __restrict__ bc,
                                                  const float* __restrict__ alog,
                                                  const float* __restrict__ Hinit,
                                                  const float* __restrict__ Dp,
                                                  const float* __restrict__ xz,
                                                  short* __restrict__ y) {
  const int j = blockIdx.x;
  const int d = blockIdx.y * 256 + threadIdx.x;
  __shared__ float sB[LCH][Nn], sC[LCH][Nn];
  for (int q = threadIdx.x; q < LCH * Nn; q += 256) {
    int tt = q >> 4, n = q & 15;
    size_t r = (size_t)(j * LCH + tt) * 32;
    sB[tt][n] = bc[r + n];
    sC[tt][n] = bc[r + 16 + n];
  }
  __syncthreads();
  float Ar[Nn], h[Nn];
  size_t hb = ((size_t)j * DIc + d) * Nn;
#pragma unroll
  for (int n = 0; n < Nn; n++) {
    Ar[n] = -__expf(alog[d * Nn + n]); h[n] = Hinit[hb + n];
  }
  float dp = Dp[d];
  const int t0 = j * LCH;
  for (int tt = 0; tt < LCH; tt++) {
    size_t gi = (size_t)(t0 + tt) * DIc + d;
    float dtv = dt[gi];
    float uv = bf2f(u[gi]);
    float dtu = dtv * uv;
    float yv = dp * uv;
#pragma unroll
    for (int n = 0; n < Nn; n++) {
      float a = __expf(dtv * Ar[n]);
      h[n] = a * h[n] + dtu * sB[tt][n];
      yv += h[n] * sC[tt][n];
    }
    float zv = xz[(size_t)(t0 + tt) * (2 * DIc) + DIc + d];
    float sz = zv / (1.f + __expf(-zv));
    y[gi] = f2bf(yv * sz);
  }
}

// ---------------- host orchestration ----------------
extern "C" void kernel_launch(void* const* d_in, const int* in_sizes, int n_in,
                              void* d_out, int out_size, void* d_ws, size_t ws_size,
                              hipStream_t stream) {
  (void)in_sizes; (void)n_in; (void)out_size; (void)ws_size;
  const int* ids = (const int*)d_in[0];
  const float* emb = (const float*)d_in[1];
  const float* in_proj_w = (const float*)d_in[2];
  const float* conv_w = (const float*)d_in[3];
  const float* conv_b = (const float*)d_in[4];
  const float* x_proj_w = (const float*)d_in[5];
  const float* dt_proj_w = (const float*)d_in[6];
  const float* dt_proj_b = (const float*)d_in[7];
  const float* A_log = (const float*)d_in[8];
  const float* D_param = (const float*)d_in[9];
  const float* out_proj_w = (const float*)d_in[10];
  const float* norm_w = (const float*)d_in[11];
  const float* norm_f_w = (const float*)d_in[12];
  const float* lm_head_w = (const float*)d_in[13];
  float* logits = (float*)d_out;

  // lm_head-phase-live buffers in d_ws; dead-before-final-GEMM scratch in d_out.
  char* ws = (char*)d_ws;
  size_t woff = 0;
  auto walloc = [&](size_t bytes) { void* p = ws + woff; woff += (bytes + 255) & ~(size_t)255; return p; };
  float* x     = (float*)walloc((size_t)Ss * Dd * 4);
  short* xfbf  = (short*)walloc((size_t)Ss * Dd * 2);
  short* w_lm  = (short*)walloc((size_t)Vv * Dd * 2);

  char* sc = (char*)d_out;
  size_t soff = 0;
  auto salloc = [&](size_t bytes) { void* p = sc + soff; soff += (bytes + 255) & ~(size_t)255; return p; };
  float* xz   = (float*)salloc((size_t)Ss * 2 * DIc * 4);
  float* dtb  = (float*)salloc((size_t)Ss * DIc * 4);
  float* bc   = (float*)salloc((size_t)Ss * 32 * 4);
  float* Ap   = (float*)salloc((size_t)NCHc * DIc * Nn * 4);
  float* Hl   = (float*)salloc((size_t)NCHc * DIc * Nn * 4);
  float* Hi   = (float*)salloc((size_t)NCHc * DIc * Nn * 4);
  short* hbf  = (short*)salloc((size_t)Ss * Dd * 2);
  short* xiC  = (short*)salloc((size_t)Ss * DIc * 2);
  short* ybf  = (short*)salloc((size_t)Ss * DIc * 2);
  short* w_in = (short*)salloc((size_t)NLay * 2 * DIc * Dd * 2);
  short* w_cat= (short*)salloc((size_t)NLay * CATR * DIc * 2);
  short* w_out= (short*)salloc((size_t)NLay * Dd * DIc * 2);

  // one batched weight-convert launch (incl. lm_head)
  CvtBatch cb2{};
  unsigned tot = 0;
  auto addseg = [&](int i, const float* s, short* d, size_t n) {
    cb2.seg[i].s = s; cb2.seg[i].d = d; cb2.seg[i].n4 = (unsigned)(n / 4);
    tot += (unsigned)(n / 4);
  };
  addseg(0, in_proj_w, w_in, (size_t)NLay * 2 * DIc * Dd);
  addseg(1, out_proj_w, w_out, (size_t)NLay * Dd * DIc);
  addseg(2, lm_head_w, w_lm, (size_t)Vv * Dd);
  addseg(3, dt_proj_w, w_cat, (size_t)DIc * DIc);
  addseg(4, x_proj_w, w_cat + (size_t)DIc * DIc, (size_t)2 * Nn * DIc);
  addseg(5, dt_proj_w + (size_t)DIc * DIc, w_cat + (size_t)CATR * DIc, (size_t)DIc * DIc);
  addseg(6, x_proj_w + (size_t)2 * Nn * DIc,
         w_cat + (size_t)CATR * DIc + (size_t)DIc * DIc, (size_t)2 * Nn * DIc);
  cb2.tot4 = tot;
  cvt_all_k<<<dim3(4096), dim3(256), 0, stream>>>(cb2);

  // fused embed + layer-0 rmsnorm
  embed_norm_k<<<dim3(Ss), dim3(256), 0, stream>>>(ids, emb, norm_w, x, hbf);

  for (int l = 0; l < NLay; l++) {
    if (l > 0)
      rmsnorm_k<<<dim3(Ss), dim3(256), 0, stream>>>(x, norm_w + (size_t)l * Dd, hbf);
    gemm_ring<128, 128, 2, 2, false, false><<<dim3(512), dim3(256), 0, stream>>>(
        hbf, w_in + (size_t)l * 2 * DIc * Dd, xz, nullptr, nullptr, Ss, 2 * DIc, Dd, 16);
    conv_silu_k<<<dim3(Ss * DIc / 4 / 256), dim3(256), 0, stream>>>(
        xz, conv_w + (size_t)l * DIc * Kc, conv_b + (size_t)l * DIc, xiC);
    gemm_ring<128, 128, 2, 2, false, true><<<dim3(272), dim3(256), 0, stream>>>(
        xiC, w_cat + (size_t)l * CATR * DIc, dtb, dt_proj_b + (size_t)l * DIc, bc,
        Ss, CATR, DIc, 16);
    scan_pass1<<<dim3(NCHc, DIc / 256), dim3(256), 0, stream>>>(
        dtb, xiC, bc, A_log + (size_t)l * DIc * Nn, Ap, Hl);
    scan_combine<<<dim3(DIc * Nn / 256), dim3(256), 0, stream>>>(Ap, Hl, Hi);
    scan_pass2<<<dim3(NCHc, DIc / 256), dim3(256), 0, stream>>>(
        dtb, xiC, bc, A_log + (size_t)l * DIc * Nn, Hi,
        D_param + (size_t)l * DIc, xz, ybf);
    gemm_ring<128, 128, 2, 2, true, false><<<dim3(128), dim3(256), 0, stream>>>(
        ybf, w_out + (size_t)l * Dd * DIc, x, x, nullptr, Ss, Dd, DIc, 16);
  }

  rmsnorm_k<<<dim3(Ss), dim3(256), 0, stream>>>(x, norm_f_w, xfbf);
  // lm_head: 8 x 125 = 1000 blocks, round-3 gemm256 (best measured)
  gemm256<<<dim3(1000), dim3(512), 0, stream>>>(xfbf, w_lm, logits, Ss, Vv, Dd, 8);
}